// Round 10
// baseline (677.108 us; speedup 1.0000x reference)
//
#include <hip/hip_runtime.h>
#include <hip/hip_bf16.h>

#define B_  4
#define S_  2048
#define D_  1024
#define H_  16
#define DH_ 64
#define M_  (B_*S_)   // 8192

typedef short bf16x8 __attribute__((ext_vector_type(8)));   // 8 bf16 = 4 VGPR
typedef float f32x4  __attribute__((ext_vector_type(4)));
typedef unsigned short u16;

__device__ __forceinline__ u16 f2b(float x) {
    union { __hip_bfloat16 h; u16 u; } c; c.h = __float2bfloat16(x); return c.u;
}

// global -> LDS direct (16B per lane). LDS dst is wave-uniform base + lane*16;
// global src is per-lane (pre-swizzle applied there, rule #21/m173).
__device__ __forceinline__ void gl_lds16(const u16* g, u16* l) {
    __builtin_amdgcn_global_load_lds(
        (const __attribute__((address_space(1))) unsigned int*)g,
        (__attribute__((address_space(3))) unsigned int*)l,
        16, 0, 0);
}

// ---------------- fp32 -> bf16 bulk convert, q/k/v in one launch -------------
__global__ __launch_bounds__(256)
void cvt3(const float* __restrict__ q, const float* __restrict__ k,
          const float* __restrict__ v,
          u16* __restrict__ qb, u16* __restrict__ kb, u16* __restrict__ vb)
{
    const float* src = blockIdx.y == 0 ? q : (blockIdx.y == 1 ? k : v);
    u16*         dst = blockIdx.y == 0 ? qb : (blockIdx.y == 1 ? kb : vb);
    const int i = blockIdx.x*256 + threadIdx.x;      // 0..2^20-1 exact
    float4 a = ((const float4*)src)[2*i];
    float4 b = ((const float4*)src)[2*i+1];
    union { u16 u[8]; uint4 v4; } r;
    r.u[0]=f2b(a.x); r.u[1]=f2b(a.y); r.u[2]=f2b(a.z); r.u[3]=f2b(a.w);
    r.u[4]=f2b(b.x); r.u[5]=f2b(b.y); r.u[6]=f2b(b.z); r.u[7]=f2b(b.w);
    ((uint4*)dst)[i] = r.v4;
}

// ---------------- W[k][n] fp32 -> Wt[n][k] bf16, all four in one launch ------
__global__ __launch_bounds__(256)
void wtrans4(const float* __restrict__ Wq, const float* __restrict__ Wk,
             const float* __restrict__ Wv, const float* __restrict__ Wo,
             u16* __restrict__ Wqt, u16* __restrict__ Wkt,
             u16* __restrict__ Wvt, u16* __restrict__ Wot)
{
    const int z = blockIdx.z;
    const float* W  = z==0 ? Wq  : (z==1 ? Wk  : (z==2 ? Wv  : Wo));
    u16*         Wt = z==0 ? Wqt : (z==1 ? Wkt : (z==2 ? Wvt : Wot));
    __shared__ u16 Ts[64][80];
    const int t = threadIdx.x;
    const int k0 = blockIdx.x*64, n0 = blockIdx.y*64;
    const int kr = t >> 4, nc = (t & 15)*4;
    #pragma unroll
    for (int i = 0; i < 4; ++i) {
        const int kk = kr + i*16;
        float4 wv = *(const float4*)(W + (size_t)(k0 + kk)*D_ + n0 + nc);
        Ts[nc+0][kk] = f2b(wv.x); Ts[nc+1][kk] = f2b(wv.y);
        Ts[nc+2][kk] = f2b(wv.z); Ts[nc+3][kk] = f2b(wv.w);
    }
    __syncthreads();
    const int nr = t >> 2, kc = (t & 3)*16;
    u16* dst = Wt + (size_t)(n0 + nr)*D_ + k0 + kc;
    *(uint4*)(dst)     = *(const uint4*)(&Ts[nr][kc]);
    *(uint4*)(dst + 8) = *(const uint4*)(&Ts[nr][kc + 8]);
}

// ---------------- QKV projection GEMM, one launch (z selects) ----------------
__global__ __launch_bounds__(256)
void proj_qkv(const u16* __restrict__ qb, const u16* __restrict__ kb,
              const u16* __restrict__ vb,
              const u16* __restrict__ Wqt, const u16* __restrict__ Wkt,
              const u16* __restrict__ Wvt,
              const float* __restrict__ bq, const float* __restrict__ bk,
              const float* __restrict__ bv,
              u16* __restrict__ Qhb, u16* __restrict__ Khb,
              u16* __restrict__ Vtb)
{
    const int z = blockIdx.z;
    const u16* Ab     = z==0 ? qb  : (z==1 ? kb  : vb);
    const u16* Wt     = z==0 ? Wqt : (z==1 ? Wkt : Wvt);
    const float* bias = z==0 ? bq  : (z==1 ? bk  : bv);

    const int lin = blockIdx.y*64 + blockIdx.x;      // 0..511
    const int cx = lin & 7, idx = lin >> 3;
    const int nx = cx*8 + (idx & 7), ny = idx >> 3;  // bijective
    const int m0 = nx*128, n0 = ny*128;

    __shared__ u16 AsU[128*64];
    __shared__ u16 BsU[128*64];
    const int t = threadIdx.x;
    const int w = t >> 6, lane = t & 63;
    const int lo = lane & 15, g4 = lane >> 4;
    const int wr = w >> 1, wc = w & 1;
    const int wbase = w*64;

    const f32x4 zero = {0.f, 0.f, 0.f, 0.f};
    f32x4 acc[4][4];
    #pragma unroll
    for (int mi = 0; mi < 4; ++mi)
        #pragma unroll
        for (int ni = 0; ni < 4; ++ni) acc[mi][ni] = zero;

    for (int k0 = 0; k0 < 1024; k0 += 64) {
        __syncthreads();
        #pragma unroll
        for (int c = 0; c < 4; ++c) {
            const int sidx = c*256 + wbase + lane;
            const int row = sidx >> 3;
            const int gblk = (sidx & 7) ^ (row & 7);
            gl_lds16(Ab + (size_t)(m0+row)*D_ + k0 + gblk*8, AsU + (size_t)(c*256 + wbase)*8);
            gl_lds16(Wt + (size_t)(n0+row)*D_ + k0 + gblk*8, BsU + (size_t)(c*256 + wbase)*8);
        }
        __syncthreads();
        #pragma unroll
        for (int ks = 0; ks < 2; ++ks) {
            bf16x8 af[4], bfr[4];
            #pragma unroll
            for (int mi = 0; mi < 4; ++mi) {
                const int row = wr*64 + mi*16 + lo;
                af[mi] = *(const bf16x8*)(AsU + row*64 + (((ks*4+g4) ^ (lo&7))*8));
            }
            #pragma unroll
            for (int ni = 0; ni < 4; ++ni) {
                const int row = wc*64 + ni*16 + lo;
                bfr[ni] = *(const bf16x8*)(BsU + row*64 + (((ks*4+g4) ^ (lo&7))*8));
            }
            #pragma unroll
            for (int mi = 0; mi < 4; ++mi)
                #pragma unroll
                for (int ni = 0; ni < 4; ++ni)
                    acc[mi][ni] = __builtin_amdgcn_mfma_f32_16x16x32_bf16(
                        af[mi], bfr[ni], acc[mi][ni], 0, 0, 0);
        }
    }

    if (z < 2) {
        u16* C = z==0 ? Qhb : Khb;
        #pragma unroll
        for (int ni = 0; ni < 4; ++ni) {
            const int n = n0 + wc*64 + ni*16 + lo;
            const float bb = bias[n];
            #pragma unroll
            for (int mi = 0; mi < 4; ++mi)
                #pragma unroll
                for (int j = 0; j < 4; ++j) {
                    const size_t m = (size_t)(m0 + wr*64 + mi*16 + g4*4 + j);
                    C[m*D_ + n] = f2b(acc[mi][ni][j] + bb);
                }
        }
    } else {
        // transposed: Vt[b*D_ + n][s], s = within-batch row
        const int bb_ = m0 >> 11;
        const int sbase = (m0 & 2047) + wr*64;
        #pragma unroll
        for (int ni = 0; ni < 4; ++ni) {
            const int n = n0 + wc*64 + ni*16 + lo;
            const float bv_ = bias[n];
            u16* vrow = Vtb + (size_t)(bb_*D_ + n)*S_ + sbase;
            #pragma unroll
            for (int mi = 0; mi < 4; ++mi) {
                union { u16 u[4]; uint2 v2; } pk;
                #pragma unroll
                for (int j = 0; j < 4; ++j) pk.u[j] = f2b(acc[mi][ni][j] + bv_);
                *(uint2*)(vrow + mi*16 + g4*4) = pk.v2;  // 8B, aligned
            }
        }
    }
}

// ---------------- fused attention, single kernel, two block-local loops ------
// loop1: QK^T + exp + rowsum (register-only). loop2: QK^T recompute (bitwise-
// identical exp) + PLAIN scalar store of normalized attn (L2 write-back, like
// the 6.5TB/s fills; round-10 A/B vs nontemporal) + P->LDS + PV MFMA + ctx.
__global__ __launch_bounds__(256)
void attn_fused2(const u16* __restrict__ Qh, const u16* __restrict__ Kh,
                 const u16* __restrict__ Vt,
                 u16* __restrict__ ctxb, float* __restrict__ attn)
{
    __shared__ u16 Plds[4*2048];    // per-wave 32q x 64key, XOR-swizzled
    const int t = threadIdx.x, w = t >> 6, lane = t & 63;
    const int lo = lane & 15, g4 = lane >> 4;

    const int lin = (blockIdx.z*16 + blockIdx.y)*16 + blockIdx.x;  // 0..1023
    const int cx = lin & 7, idx = lin >> 3;
    const int nl = cx*128 + idx;                  // bijective chunked
    const int qb_ = nl & 15, bh = nl >> 4;
    const int h = bh & 15, b = bh >> 4;
    const int qbase = qb_*128 + w*32;
    u16* Pw = Plds + w*2048;

    bf16x8 qf[2][2];
    #pragma unroll
    for (int qs = 0; qs < 2; ++qs)
        #pragma unroll
        for (int ks = 0; ks < 2; ++ks)
            qf[qs][ks] = *(const bf16x8*)(Qh + (size_t)(b*S_ + qbase + qs*16 + lo)*D_ + h*DH_ + ks*32 + g4*8);

    const f32x4 zero = {0.f, 0.f, 0.f, 0.f};

    // ---------------- loop1: rowsums only ----------------
    float rs[2][4] = {};
    for (int kt = 0; kt < 32; ++kt) {
        const size_t kbase = (size_t)(b*S_ + kt*64)*D_ + h*DH_;
        f32x4 sacc[2][4];
        #pragma unroll
        for (int qs = 0; qs < 2; ++qs)
            #pragma unroll
            for (int ni = 0; ni < 4; ++ni) sacc[qs][ni] = zero;
        __builtin_amdgcn_s_setprio(1);
        #pragma unroll
        for (int ks = 0; ks < 2; ++ks)
            #pragma unroll
            for (int ni = 0; ni < 4; ++ni) {
                const bf16x8 kf = *(const bf16x8*)(Kh + kbase + (size_t)(ni*16 + lo)*D_ + ks*32 + g4*8);
                sacc[0][ni] = __builtin_amdgcn_mfma_f32_16x16x32_bf16(qf[0][ks], kf, sacc[0][ni], 0, 0, 0);
                sacc[1][ni] = __builtin_amdgcn_mfma_f32_16x16x32_bf16(qf[1][ks], kf, sacc[1][ni], 0, 0, 0);
            }
        __builtin_amdgcn_s_setprio(0);
        #pragma unroll
        for (int qs = 0; qs < 2; ++qs)
            #pragma unroll
            for (int ni = 0; ni < 4; ++ni)
                #pragma unroll
                for (int j = 0; j < 4; ++j)
                    rs[qs][j] += __expf(sacc[qs][ni][j] * 0.125f);
    }

    float invp[2][4];
    #pragma unroll
    for (int qs = 0; qs < 2; ++qs)
        #pragma unroll
        for (int j = 0; j < 4; ++j) {
            float r = rs[qs][j];
            r += __shfl_xor(r, 1); r += __shfl_xor(r, 2);
            r += __shfl_xor(r, 4); r += __shfl_xor(r, 8);
            invp[qs][j] = 1.0f / r;
        }

    // ---------------- loop2: recompute + store + PV ----------------
    size_t vtb[4];
    #pragma unroll
    for (int ni = 0; ni < 4; ++ni)
        vtb[ni] = (size_t)(b*D_ + h*DH_ + ni*16 + lo)*S_;

    // attn row base for this lane's rows: q = qbase + qs*16 + g4*4 + j
    float* abase = attn + ((size_t)(b*H_ + h)*S_ + qbase + g4*4)*S_;

    f32x4 cacc[2][4];
    #pragma unroll
    for (int qs = 0; qs < 2; ++qs)
        #pragma unroll
        for (int ni = 0; ni < 4; ++ni) cacc[qs][ni] = zero;

    for (int kt = 0; kt < 32; ++kt) {
        const size_t kbase = (size_t)(b*S_ + kt*64)*D_ + h*DH_;
        f32x4 sacc[2][4];
        #pragma unroll
        for (int qs = 0; qs < 2; ++qs)
            #pragma unroll
            for (int ni = 0; ni < 4; ++ni) sacc[qs][ni] = zero;
        __builtin_amdgcn_s_setprio(1);
        #pragma unroll
        for (int ks = 0; ks < 2; ++ks)
            #pragma unroll
            for (int ni = 0; ni < 4; ++ni) {
                const bf16x8 kf = *(const bf16x8*)(Kh + kbase + (size_t)(ni*16 + lo)*D_ + ks*32 + g4*8);
                sacc[0][ni] = __builtin_amdgcn_mfma_f32_16x16x32_bf16(qf[0][ks], kf, sacc[0][ni], 0, 0, 0);
                sacc[1][ni] = __builtin_amdgcn_mfma_f32_16x16x32_bf16(qf[1][ks], kf, sacc[1][ni], 0, 0, 0);
            }
        __builtin_amdgcn_s_setprio(0);
        // exp -> P LDS (unnormalized) + PLAIN store normalized attn
        #pragma unroll
        for (int qs = 0; qs < 2; ++qs)
            #pragma unroll
            for (int ni = 0; ni < 4; ++ni)
                #pragma unroll
                for (int j = 0; j < 4; ++j) {
                    const float p = __expf(sacc[qs][ni][j] * 0.125f);
                    const int row = qs*16 + g4*4 + j, key = ni*16 + lo;
                    Pw[row*64 + (((key >> 3) ^ (row & 7))*8) + (key & 7)] = f2b(p);
                    abase[((size_t)(qs*16 + j))*S_ + kt*64 + key] = p * invp[qs][j];
                }
        asm volatile("" ::: "memory");
        __builtin_amdgcn_s_setprio(1);
        #pragma unroll
        for (int ks = 0; ks < 2; ++ks) {
            bf16x8 vf[4];
            #pragma unroll
            for (int ni = 0; ni < 4; ++ni)
                vf[ni] = *(const bf16x8*)(Vt + vtb[ni] + kt*64 + ks*32 + g4*8);
            #pragma unroll
            for (int qs = 0; qs < 2; ++qs) {
                const int prow = qs*16 + lo;
                const bf16x8 pa = *(const bf16x8*)(Pw + prow*64 + (((ks*4 + g4) ^ (lo & 7))*8));
                #pragma unroll
                for (int ni = 0; ni < 4; ++ni)
                    cacc[qs][ni] = __builtin_amdgcn_mfma_f32_16x16x32_bf16(pa, vf[ni], cacc[qs][ni], 0, 0, 0);
            }
        }
        __builtin_amdgcn_s_setprio(0);
        asm volatile("" ::: "memory");
    }

    #pragma unroll
    for (int qs = 0; qs < 2; ++qs)
        #pragma unroll
        for (int j = 0; j < 4; ++j) {
            const float inv = invp[qs][j];
            #pragma unroll
            for (int ni = 0; ni < 4; ++ni)
                ctxb[(size_t)(b*S_ + qbase + qs*16 + g4*4 + j)*D_ + h*DH_ + ni*16 + lo] =
                    f2b(cacc[qs][ni][j] * inv);
        }
}

// ---------------- output GEMM: out[M][1024] = ctx@Wo + bo (fp32 out) ---------
__global__ __launch_bounds__(256)
void gemm_out(const u16* __restrict__ Ab, const u16* __restrict__ Wt,
              const float* __restrict__ bias, float* __restrict__ Cf)
{
    const int lin = blockIdx.y*64 + blockIdx.x;
    const int cx = lin & 7, idx = lin >> 3;
    const int nx = cx*8 + (idx & 7), ny = idx >> 3;
    const int m0 = nx*128, n0 = ny*128;

    __shared__ u16 AsU[128*64];
    __shared__ u16 BsU[128*64];
    const int t = threadIdx.x;
    const int w = t >> 6, lane = t & 63;
    const int lo = lane & 15, g4 = lane >> 4;
    const int wr = w >> 1, wc = w & 1;
    const int wbase = w*64;

    const f32x4 zero = {0.f, 0.f, 0.f, 0.f};
    f32x4 acc[4][4];
    #pragma unroll
    for (int mi = 0; mi < 4; ++mi)
        #pragma unroll
        for (int ni = 0; ni < 4; ++ni) acc[mi][ni] = zero;

    for (int k0 = 0; k0 < 1024; k0 += 64) {
        __syncthreads();
        #pragma unroll
        for (int c = 0; c < 4; ++c) {
            const int sidx = c*256 + wbase + lane;
            const int row = sidx >> 3;
            const int gblk = (sidx & 7) ^ (row & 7);
            gl_lds16(Ab + (size_t)(m0+row)*D_ + k0 + gblk*8, AsU + (size_t)(c*256 + wbase)*8);
            gl_lds16(Wt + (size_t)(n0+row)*D_ + k0 + gblk*8, BsU + (size_t)(c*256 + wbase)*8);
        }
        __syncthreads();
        #pragma unroll
        for (int ks = 0; ks < 2; ++ks) {
            bf16x8 af[4], bfr[4];
            #pragma unroll
            for (int mi = 0; mi < 4; ++mi) {
                const int row = wr*64 + mi*16 + lo;
                af[mi] = *(const bf16x8*)(AsU + row*64 + (((ks*4+g4) ^ (lo&7))*8));
            }
            #pragma unroll
            for (int ni = 0; ni < 4; ++ni) {
                const int row = wc*64 + ni*16 + lo;
                bfr[ni] = *(const bf16x8*)(BsU + row*64 + (((ks*4+g4) ^ (lo&7))*8));
            }
            #pragma unroll
            for (int mi = 0; mi < 4; ++mi)
                #pragma unroll
                for (int ni = 0; ni < 4; ++ni)
                    acc[mi][ni] = __builtin_amdgcn_mfma_f32_16x16x32_bf16(
                        af[mi], bfr[ni], acc[mi][ni], 0, 0, 0);
        }
    }

    #pragma unroll
    for (int ni = 0; ni < 4; ++ni) {
        const int n = n0 + wc*64 + ni*16 + lo;
        const float bb = bias[n];
        #pragma unroll
        for (int mi = 0; mi < 4; ++mi)
            #pragma unroll
            for (int j = 0; j < 4; ++j) {
                const size_t m = (size_t)(m0 + wr*64 + mi*16 + g4*4 + j);
                Cf[m*D_ + n] = acc[mi][ni][j] + bb;
            }
    }
}

// ----------------------------------------------------------------------------
extern "C" void kernel_launch(void* const* d_in, const int* in_sizes, int n_in,
                              void* d_out, int out_size, void* d_ws, size_t ws_size,
                              hipStream_t stream)
{
    (void)in_sizes; (void)n_in; (void)out_size; (void)ws_size;
    const float* v  = (const float*)d_in[0];
    const float* k  = (const float*)d_in[1];
    const float* q  = (const float*)d_in[2];
    const float* Wq = (const float*)d_in[3];
    const float* bq = (const float*)d_in[4];
    const float* Wk = (const float*)d_in[5];
    const float* bk = (const float*)d_in[6];
    const float* Wv = (const float*)d_in[7];
    const float* bv = (const float*)d_in[8];
    const float* Wo = (const float*)d_in[9];
    const float* bo = (const float*)d_in[10];

    float* out  = (float*)d_out;                  // (B,S,D) fp32
    float* attn = out + (size_t)M_*D_;            // (B,H,S,S) fp32

    u16* qb  = (u16*)d_ws;
    u16* kb  = qb  + (size_t)M_*D_;
    u16* vb  = kb  + (size_t)M_*D_;
    u16* Wqt = vb  + (size_t)M_*D_;
    u16* Wkt = Wqt + (size_t)D_*D_;
    u16* Wvt = Wkt + (size_t)D_*D_;
    u16* Wot = Wvt + (size_t)D_*D_;
    u16* Qhb = Wot + (size_t)D_*D_;
    u16* Khb = Qhb + (size_t)M_*D_;
    u16* Vtb = Khb + (size_t)M_*D_;
    u16* ctxb = qb;                               // reuse (dead after q-proj)

    dim3 b256(256);

    cvt3       <<<dim3(4096, 3),   b256, 0, stream>>>(q, k, v, qb, kb, vb);
    wtrans4    <<<dim3(16, 16, 4), b256, 0, stream>>>(Wq, Wk, Wv, Wo, Wqt, Wkt, Wvt, Wot);
    proj_qkv   <<<dim3(64, 8, 3),  b256, 0, stream>>>(qb, kb, vb, Wqt, Wkt, Wvt,
                                                      bq, bk, bv, Qhb, Khb, Vtb);
    attn_fused2<<<dim3(16, 16, 4), b256, 0, stream>>>(Qhb, Khb, Vtb, ctxb, attn);
    gemm_out   <<<dim3(64, 8),     b256, 0, stream>>>(ctxb, Wot, bo, out);
}

// Round 11
// 511.892 us; speedup vs baseline: 1.3228x; 1.3228x over previous
//
#include <hip/hip_runtime.h>
#include <hip/hip_bf16.h>

#define B_  4
#define S_  2048
#define D_  1024
#define H_  16
#define DH_ 64
#define M_  (B_*S_)   // 8192

typedef short bf16x8 __attribute__((ext_vector_type(8)));   // 8 bf16 = 4 VGPR
typedef float f32x4  __attribute__((ext_vector_type(4)));
typedef unsigned short u16;

__device__ __forceinline__ u16 f2b(float x) {
    union { __hip_bfloat16 h; u16 u; } c; c.h = __float2bfloat16(x); return c.u;
}

// global -> LDS direct (16B per lane). LDS dst is wave-uniform base + lane*16;
// global src is per-lane (pre-swizzle applied there, rule #21/m173).
__device__ __forceinline__ void gl_lds16(const u16* g, u16* l) {
    __builtin_amdgcn_global_load_lds(
        (const __attribute__((address_space(1))) unsigned int*)g,
        (__attribute__((address_space(3))) unsigned int*)l,
        16, 0, 0);
}

// ---------------- fp32 -> bf16 bulk convert, q/k/v in one launch -------------
__global__ __launch_bounds__(256)
void cvt3(const float* __restrict__ q, const float* __restrict__ k,
          const float* __restrict__ v,
          u16* __restrict__ qb, u16* __restrict__ kb, u16* __restrict__ vb)
{
    const float* src = blockIdx.y == 0 ? q : (blockIdx.y == 1 ? k : v);
    u16*         dst = blockIdx.y == 0 ? qb : (blockIdx.y == 1 ? kb : vb);
    const int i = blockIdx.x*256 + threadIdx.x;      // 0..2^20-1 exact
    float4 a = ((const float4*)src)[2*i];
    float4 b = ((const float4*)src)[2*i+1];
    union { u16 u[8]; uint4 v4; } r;
    r.u[0]=f2b(a.x); r.u[1]=f2b(a.y); r.u[2]=f2b(a.z); r.u[3]=f2b(a.w);
    r.u[4]=f2b(b.x); r.u[5]=f2b(b.y); r.u[6]=f2b(b.z); r.u[7]=f2b(b.w);
    ((uint4*)dst)[i] = r.v4;
}

// ---------------- W[k][n] fp32 -> Wt[n][k] bf16, all four in one launch ------
__global__ __launch_bounds__(256)
void wtrans4(const float* __restrict__ Wq, const float* __restrict__ Wk,
             const float* __restrict__ Wv, const float* __restrict__ Wo,
             u16* __restrict__ Wqt, u16* __restrict__ Wkt,
             u16* __restrict__ Wvt, u16* __restrict__ Wot)
{
    const int z = blockIdx.z;
    const float* W  = z==0 ? Wq  : (z==1 ? Wk  : (z==2 ? Wv  : Wo));
    u16*         Wt = z==0 ? Wqt : (z==1 ? Wkt : (z==2 ? Wvt : Wot));
    __shared__ u16 Ts[64][80];
    const int t = threadIdx.x;
    const int k0 = blockIdx.x*64, n0 = blockIdx.y*64;
    const int kr = t >> 4, nc = (t & 15)*4;
    #pragma unroll
    for (int i = 0; i < 4; ++i) {
        const int kk = kr + i*16;
        float4 wv = *(const float4*)(W + (size_t)(k0 + kk)*D_ + n0 + nc);
        Ts[nc+0][kk] = f2b(wv.x); Ts[nc+1][kk] = f2b(wv.y);
        Ts[nc+2][kk] = f2b(wv.z); Ts[nc+3][kk] = f2b(wv.w);
    }
    __syncthreads();
    const int nr = t >> 2, kc = (t & 3)*16;
    u16* dst = Wt + (size_t)(n0 + nr)*D_ + k0 + kc;
    *(uint4*)(dst)     = *(const uint4*)(&Ts[nr][kc]);
    *(uint4*)(dst + 8) = *(const uint4*)(&Ts[nr][kc + 8]);
}

// ---------------- QKV projection GEMM, one launch (z selects) ----------------
__global__ __launch_bounds__(256)
void proj_qkv(const u16* __restrict__ qb, const u16* __restrict__ kb,
              const u16* __restrict__ vb,
              const u16* __restrict__ Wqt, const u16* __restrict__ Wkt,
              const u16* __restrict__ Wvt,
              const float* __restrict__ bq, const float* __restrict__ bk,
              const float* __restrict__ bv,
              u16* __restrict__ Qhb, u16* __restrict__ Khb,
              u16* __restrict__ Vtb)
{
    const int z = blockIdx.z;
    const u16* Ab     = z==0 ? qb  : (z==1 ? kb  : vb);
    const u16* Wt     = z==0 ? Wqt : (z==1 ? Wkt : Wvt);
    const float* bias = z==0 ? bq  : (z==1 ? bk  : bv);

    const int lin = blockIdx.y*64 + blockIdx.x;      // 0..511
    const int cx = lin & 7, idx = lin >> 3;
    const int nx = cx*8 + (idx & 7), ny = idx >> 3;  // bijective
    const int m0 = nx*128, n0 = ny*128;

    __shared__ u16 AsU[128*64];
    __shared__ u16 BsU[128*64];
    const int t = threadIdx.x;
    const int w = t >> 6, lane = t & 63;
    const int lo = lane & 15, g4 = lane >> 4;
    const int wr = w >> 1, wc = w & 1;
    const int wbase = w*64;

    const f32x4 zero = {0.f, 0.f, 0.f, 0.f};
    f32x4 acc[4][4];
    #pragma unroll
    for (int mi = 0; mi < 4; ++mi)
        #pragma unroll
        for (int ni = 0; ni < 4; ++ni) acc[mi][ni] = zero;

    for (int k0 = 0; k0 < 1024; k0 += 64) {
        __syncthreads();
        #pragma unroll
        for (int c = 0; c < 4; ++c) {
            const int sidx = c*256 + wbase + lane;
            const int row = sidx >> 3;
            const int gblk = (sidx & 7) ^ (row & 7);
            gl_lds16(Ab + (size_t)(m0+row)*D_ + k0 + gblk*8, AsU + (size_t)(c*256 + wbase)*8);
            gl_lds16(Wt + (size_t)(n0+row)*D_ + k0 + gblk*8, BsU + (size_t)(c*256 + wbase)*8);
        }
        __syncthreads();
        #pragma unroll
        for (int ks = 0; ks < 2; ++ks) {
            bf16x8 af[4], bfr[4];
            #pragma unroll
            for (int mi = 0; mi < 4; ++mi) {
                const int row = wr*64 + mi*16 + lo;
                af[mi] = *(const bf16x8*)(AsU + row*64 + (((ks*4+g4) ^ (lo&7))*8));
            }
            #pragma unroll
            for (int ni = 0; ni < 4; ++ni) {
                const int row = wc*64 + ni*16 + lo;
                bfr[ni] = *(const bf16x8*)(BsU + row*64 + (((ks*4+g4) ^ (lo&7))*8));
            }
            #pragma unroll
            for (int mi = 0; mi < 4; ++mi)
                #pragma unroll
                for (int ni = 0; ni < 4; ++ni)
                    acc[mi][ni] = __builtin_amdgcn_mfma_f32_16x16x32_bf16(
                        af[mi], bfr[ni], acc[mi][ni], 0, 0, 0);
        }
    }

    if (z < 2) {
        u16* C = z==0 ? Qhb : Khb;
        #pragma unroll
        for (int ni = 0; ni < 4; ++ni) {
            const int n = n0 + wc*64 + ni*16 + lo;
            const float bb = bias[n];
            #pragma unroll
            for (int mi = 0; mi < 4; ++mi)
                #pragma unroll
                for (int j = 0; j < 4; ++j) {
                    const size_t m = (size_t)(m0 + wr*64 + mi*16 + g4*4 + j);
                    C[m*D_ + n] = f2b(acc[mi][ni][j] + bb);
                }
        }
    } else {
        // transposed: Vt[b*D_ + n][s], s = within-batch row
        const int bb_ = m0 >> 11;
        const int sbase = (m0 & 2047) + wr*64;
        #pragma unroll
        for (int ni = 0; ni < 4; ++ni) {
            const int n = n0 + wc*64 + ni*16 + lo;
            const float bv_ = bias[n];
            u16* vrow = Vtb + (size_t)(bb_*D_ + n)*S_ + sbase;
            #pragma unroll
            for (int mi = 0; mi < 4; ++mi) {
                union { u16 u[4]; uint2 v2; } pk;
                #pragma unroll
                for (int j = 0; j < 4; ++j) pk.u[j] = f2b(acc[mi][ni][j] + bv_);
                *(uint2*)(vrow + mi*16 + g4*4) = pk.v2;  // 8B, aligned
            }
        }
    }
}

// ---------------- fused attention, single kernel, two block-local loops ------
// loop1: QK^T + exp + rowsum (register-only). loop2: QK^T recompute (bitwise-
// identical exp) + nt scalar store of normalized attn + P->LDS + PV MFMA + ctx.
// NO asm memory barriers in loop2 (round 11): compiler handles LDS RAW/WAR on
// the wave-wide ds ops via lgkmcnt; removing them lets V/K loads hoist and
// pipeline across kt, hiding L2 latency under the exp/store cluster.
__global__ __launch_bounds__(256)
void attn_fused2(const u16* __restrict__ Qh, const u16* __restrict__ Kh,
                 const u16* __restrict__ Vt,
                 u16* __restrict__ ctxb, float* __restrict__ attn)
{
    __shared__ u16 Plds[4*2048];    // per-wave 32q x 64key, XOR-swizzled
    const int t = threadIdx.x, w = t >> 6, lane = t & 63;
    const int lo = lane & 15, g4 = lane >> 4;

    const int lin = (blockIdx.z*16 + blockIdx.y)*16 + blockIdx.x;  // 0..1023
    const int cx = lin & 7, idx = lin >> 3;
    const int nl = cx*128 + idx;                  // bijective chunked
    const int qb_ = nl & 15, bh = nl >> 4;
    const int h = bh & 15, b = bh >> 4;
    const int qbase = qb_*128 + w*32;
    u16* Pw = Plds + w*2048;

    bf16x8 qf[2][2];
    #pragma unroll
    for (int qs = 0; qs < 2; ++qs)
        #pragma unroll
        for (int ks = 0; ks < 2; ++ks)
            qf[qs][ks] = *(const bf16x8*)(Qh + (size_t)(b*S_ + qbase + qs*16 + lo)*D_ + h*DH_ + ks*32 + g4*8);

    const f32x4 zero = {0.f, 0.f, 0.f, 0.f};

    // ---------------- loop1: rowsums only ----------------
    float rs[2][4] = {};
    for (int kt = 0; kt < 32; ++kt) {
        const size_t kbase = (size_t)(b*S_ + kt*64)*D_ + h*DH_;
        f32x4 sacc[2][4];
        #pragma unroll
        for (int qs = 0; qs < 2; ++qs)
            #pragma unroll
            for (int ni = 0; ni < 4; ++ni) sacc[qs][ni] = zero;
        __builtin_amdgcn_s_setprio(1);
        #pragma unroll
        for (int ks = 0; ks < 2; ++ks)
            #pragma unroll
            for (int ni = 0; ni < 4; ++ni) {
                const bf16x8 kf = *(const bf16x8*)(Kh + kbase + (size_t)(ni*16 + lo)*D_ + ks*32 + g4*8);
                sacc[0][ni] = __builtin_amdgcn_mfma_f32_16x16x32_bf16(qf[0][ks], kf, sacc[0][ni], 0, 0, 0);
                sacc[1][ni] = __builtin_amdgcn_mfma_f32_16x16x32_bf16(qf[1][ks], kf, sacc[1][ni], 0, 0, 0);
            }
        __builtin_amdgcn_s_setprio(0);
        #pragma unroll
        for (int qs = 0; qs < 2; ++qs)
            #pragma unroll
            for (int ni = 0; ni < 4; ++ni)
                #pragma unroll
                for (int j = 0; j < 4; ++j)
                    rs[qs][j] += __expf(sacc[qs][ni][j] * 0.125f);
    }

    float invp[2][4];
    #pragma unroll
    for (int qs = 0; qs < 2; ++qs)
        #pragma unroll
        for (int j = 0; j < 4; ++j) {
            float r = rs[qs][j];
            r += __shfl_xor(r, 1); r += __shfl_xor(r, 2);
            r += __shfl_xor(r, 4); r += __shfl_xor(r, 8);
            invp[qs][j] = 1.0f / r;
        }

    // ---------------- loop2: recompute + store + PV ----------------
    size_t vtb[4];
    #pragma unroll
    for (int ni = 0; ni < 4; ++ni)
        vtb[ni] = (size_t)(b*D_ + h*DH_ + ni*16 + lo)*S_;

    // attn row base for this lane's rows: q = qbase + qs*16 + g4*4 + j
    float* abase = attn + ((size_t)(b*H_ + h)*S_ + qbase + g4*4)*S_;

    f32x4 cacc[2][4];
    #pragma unroll
    for (int qs = 0; qs < 2; ++qs)
        #pragma unroll
        for (int ni = 0; ni < 4; ++ni) cacc[qs][ni] = zero;

    for (int kt = 0; kt < 32; ++kt) {
        const size_t kbase = (size_t)(b*S_ + kt*64)*D_ + h*DH_;
        f32x4 sacc[2][4];
        #pragma unroll
        for (int qs = 0; qs < 2; ++qs)
            #pragma unroll
            for (int ni = 0; ni < 4; ++ni) sacc[qs][ni] = zero;
        __builtin_amdgcn_s_setprio(1);
        #pragma unroll
        for (int ks = 0; ks < 2; ++ks)
            #pragma unroll
            for (int ni = 0; ni < 4; ++ni) {
                const bf16x8 kf = *(const bf16x8*)(Kh + kbase + (size_t)(ni*16 + lo)*D_ + ks*32 + g4*8);
                sacc[0][ni] = __builtin_amdgcn_mfma_f32_16x16x32_bf16(qf[0][ks], kf, sacc[0][ni], 0, 0, 0);
                sacc[1][ni] = __builtin_amdgcn_mfma_f32_16x16x32_bf16(qf[1][ks], kf, sacc[1][ni], 0, 0, 0);
            }
        __builtin_amdgcn_s_setprio(0);
        // exp -> P LDS (unnormalized) + nt-store normalized attn
        #pragma unroll
        for (int qs = 0; qs < 2; ++qs)
            #pragma unroll
            for (int ni = 0; ni < 4; ++ni)
                #pragma unroll
                for (int j = 0; j < 4; ++j) {
                    const float p = __expf(sacc[qs][ni][j] * 0.125f);
                    const int row = qs*16 + g4*4 + j, key = ni*16 + lo;
                    Pw[row*64 + (((key >> 3) ^ (row & 7))*8) + (key & 7)] = f2b(p);
                    __builtin_nontemporal_store(p * invp[qs][j],
                        abase + ((size_t)(qs*16 + j))*S_ + kt*64 + key);
                }
        __builtin_amdgcn_s_setprio(1);
        #pragma unroll
        for (int ks = 0; ks < 2; ++ks) {
            bf16x8 vf[4];
            #pragma unroll
            for (int ni = 0; ni < 4; ++ni)
                vf[ni] = *(const bf16x8*)(Vt + vtb[ni] + kt*64 + ks*32 + g4*8);
            #pragma unroll
            for (int qs = 0; qs < 2; ++qs) {
                const int prow = qs*16 + lo;
                const bf16x8 pa = *(const bf16x8*)(Pw + prow*64 + (((ks*4 + g4) ^ (lo & 7))*8));
                #pragma unroll
                for (int ni = 0; ni < 4; ++ni)
                    cacc[qs][ni] = __builtin_amdgcn_mfma_f32_16x16x32_bf16(pa, vf[ni], cacc[qs][ni], 0, 0, 0);
            }
        }
        __builtin_amdgcn_s_setprio(0);
    }

    #pragma unroll
    for (int qs = 0; qs < 2; ++qs)
        #pragma unroll
        for (int j = 0; j < 4; ++j) {
            const float inv = invp[qs][j];
            #pragma unroll
            for (int ni = 0; ni < 4; ++ni)
                ctxb[(size_t)(b*S_ + qbase + qs*16 + g4*4 + j)*D_ + h*DH_ + ni*16 + lo] =
                    f2b(cacc[qs][ni][j] * inv);
        }
}

// ---------------- output GEMM: out[M][1024] = ctx@Wo + bo (fp32 out) ---------
__global__ __launch_bounds__(256)
void gemm_out(const u16* __restrict__ Ab, const u16* __restrict__ Wt,
              const float* __restrict__ bias, float* __restrict__ Cf)
{
    const int lin = blockIdx.y*64 + blockIdx.x;
    const int cx = lin & 7, idx = lin >> 3;
    const int nx = cx*8 + (idx & 7), ny = idx >> 3;
    const int m0 = nx*128, n0 = ny*128;

    __shared__ u16 AsU[128*64];
    __shared__ u16 BsU[128*64];
    const int t = threadIdx.x;
    const int w = t >> 6, lane = t & 63;
    const int lo = lane & 15, g4 = lane >> 4;
    const int wr = w >> 1, wc = w & 1;
    const int wbase = w*64;

    const f32x4 zero = {0.f, 0.f, 0.f, 0.f};
    f32x4 acc[4][4];
    #pragma unroll
    for (int mi = 0; mi < 4; ++mi)
        #pragma unroll
        for (int ni = 0; ni < 4; ++ni) acc[mi][ni] = zero;

    for (int k0 = 0; k0 < 1024; k0 += 64) {
        __syncthreads();
        #pragma unroll
        for (int c = 0; c < 4; ++c) {
            const int sidx = c*256 + wbase + lane;
            const int row = sidx >> 3;
            const int gblk = (sidx & 7) ^ (row & 7);
            gl_lds16(Ab + (size_t)(m0+row)*D_ + k0 + gblk*8, AsU + (size_t)(c*256 + wbase)*8);
            gl_lds16(Wt + (size_t)(n0+row)*D_ + k0 + gblk*8, BsU + (size_t)(c*256 + wbase)*8);
        }
        __syncthreads();
        #pragma unroll
        for (int ks = 0; ks < 2; ++ks) {
            bf16x8 af[4], bfr[4];
            #pragma unroll
            for (int mi = 0; mi < 4; ++mi) {
                const int row = wr*64 + mi*16 + lo;
                af[mi] = *(const bf16x8*)(AsU + row*64 + (((ks*4+g4) ^ (lo&7))*8));
            }
            #pragma unroll
            for (int ni = 0; ni < 4; ++ni) {
                const int row = wc*64 + ni*16 + lo;
                bfr[ni] = *(const bf16x8*)(BsU + row*64 + (((ks*4+g4) ^ (lo&7))*8));
            }
            #pragma unroll
            for (int mi = 0; mi < 4; ++mi)
                #pragma unroll
                for (int ni = 0; ni < 4; ++ni)
                    acc[mi][ni] = __builtin_amdgcn_mfma_f32_16x16x32_bf16(
                        af[mi], bfr[ni], acc[mi][ni], 0, 0, 0);
        }
    }

    #pragma unroll
    for (int ni = 0; ni < 4; ++ni) {
        const int n = n0 + wc*64 + ni*16 + lo;
        const float bb = bias[n];
        #pragma unroll
        for (int mi = 0; mi < 4; ++mi)
            #pragma unroll
            for (int j = 0; j < 4; ++j) {
                const size_t m = (size_t)(m0 + wr*64 + mi*16 + g4*4 + j);
                Cf[m*D_ + n] = acc[mi][ni][j] + bb;
            }
    }
}

// ----------------------------------------------------------------------------
extern "C" void kernel_launch(void* const* d_in, const int* in_sizes, int n_in,
                              void* d_out, int out_size, void* d_ws, size_t ws_size,
                              hipStream_t stream)
{
    (void)in_sizes; (void)n_in; (void)out_size; (void)ws_size;
    const float* v  = (const float*)d_in[0];
    const float* k  = (const float*)d_in[1];
    const float* q  = (const float*)d_in[2];
    const float* Wq = (const float*)d_in[3];
    const float* bq = (const float*)d_in[4];
    const float* Wk = (const float*)d_in[5];
    const float* bk = (const float*)d_in[6];
    const float* Wv = (const float*)d_in[7];
    const float* bv = (const float*)d_in[8];
    const float* Wo = (const float*)d_in[9];
    const float* bo = (const float*)d_in[10];

    float* out  = (float*)d_out;                  // (B,S,D) fp32
    float* attn = out + (size_t)M_*D_;            // (B,H,S,S) fp32

    u16* qb  = (u16*)d_ws;
    u16* kb  = qb  + (size_t)M_*D_;
    u16* vb  = kb  + (size_t)M_*D_;
    u16* Wqt = vb  + (size_t)M_*D_;
    u16* Wkt = Wqt + (size_t)D_*D_;
    u16* Wvt = Wkt + (size_t)D_*D_;
    u16* Wot = Wvt + (size_t)D_*D_;
    u16* Qhb = Wot + (size_t)D_*D_;
    u16* Khb = Qhb + (size_t)M_*D_;
    u16* Vtb = Khb + (size_t)M_*D_;
    u16* ctxb = qb;                               // reuse (dead after q-proj)

    dim3 b256(256);

    cvt3       <<<dim3(4096, 3),   b256, 0, stream>>>(q, k, v, qb, kb, vb);
    wtrans4    <<<dim3(16, 16, 4), b256, 0, stream>>>(Wq, Wk, Wv, Wo, Wqt, Wkt, Wvt, Wot);
    proj_qkv   <<<dim3(64, 8, 3),  b256, 0, stream>>>(qb, kb, vb, Wqt, Wkt, Wvt,
                                                      bq, bk, bv, Qhb, Khb, Vtb);
    attn_fused2<<<dim3(16, 16, 4), b256, 0, stream>>>(Qhb, Khb, Vtb, ctxb, attn);
    gemm_out   <<<dim3(64, 8),     b256, 0, stream>>>(ctxb, Wot, bo, out);
}

// Round 12
// 510.012 us; speedup vs baseline: 1.3276x; 1.0037x over previous
//
#include <hip/hip_runtime.h>
#include <hip/hip_bf16.h>

#define B_  4
#define S_  2048
#define D_  1024
#define H_  16
#define DH_ 64
#define M_  (B_*S_)   // 8192

typedef short bf16x8 __attribute__((ext_vector_type(8)));   // 8 bf16 = 4 VGPR
typedef float f32x4  __attribute__((ext_vector_type(4)));
typedef unsigned short u16;

__device__ __forceinline__ u16 f2b(float x) {
    union { __hip_bfloat16 h; u16 u; } c; c.h = __float2bfloat16(x); return c.u;
}

// global -> LDS direct (16B per lane). LDS dst is wave-uniform base + lane*16;
// global src is per-lane (pre-swizzle applied there, rule #21/m173).
__device__ __forceinline__ void gl_lds16(const u16* g, u16* l) {
    __builtin_amdgcn_global_load_lds(
        (const __attribute__((address_space(1))) unsigned int*)g,
        (__attribute__((address_space(3))) unsigned int*)l,
        16, 0, 0);
}

// ---------------- fp32 -> bf16 bulk convert, q/k/v in one launch -------------
__global__ __launch_bounds__(256)
void cvt3(const float* __restrict__ q, const float* __restrict__ k,
          const float* __restrict__ v,
          u16* __restrict__ qb, u16* __restrict__ kb, u16* __restrict__ vb)
{
    const float* src = blockIdx.y == 0 ? q : (blockIdx.y == 1 ? k : v);
    u16*         dst = blockIdx.y == 0 ? qb : (blockIdx.y == 1 ? kb : vb);
    const int i = blockIdx.x*256 + threadIdx.x;      // 0..2^20-1 exact
    float4 a = ((const float4*)src)[2*i];
    float4 b = ((const float4*)src)[2*i+1];
    union { u16 u[8]; uint4 v4; } r;
    r.u[0]=f2b(a.x); r.u[1]=f2b(a.y); r.u[2]=f2b(a.z); r.u[3]=f2b(a.w);
    r.u[4]=f2b(b.x); r.u[5]=f2b(b.y); r.u[6]=f2b(b.z); r.u[7]=f2b(b.w);
    ((uint4*)dst)[i] = r.v4;
}

// ---------------- W[k][n] fp32 -> Wt[n][k] bf16, all four in one launch ------
__global__ __launch_bounds__(256)
void wtrans4(const float* __restrict__ Wq, const float* __restrict__ Wk,
             const float* __restrict__ Wv, const float* __restrict__ Wo,
             u16* __restrict__ Wqt, u16* __restrict__ Wkt,
             u16* __restrict__ Wvt, u16* __restrict__ Wot)
{
    const int z = blockIdx.z;
    const float* W  = z==0 ? Wq  : (z==1 ? Wk  : (z==2 ? Wv  : Wo));
    u16*         Wt = z==0 ? Wqt : (z==1 ? Wkt : (z==2 ? Wvt : Wot));
    __shared__ u16 Ts[64][80];
    const int t = threadIdx.x;
    const int k0 = blockIdx.x*64, n0 = blockIdx.y*64;
    const int kr = t >> 4, nc = (t & 15)*4;
    #pragma unroll
    for (int i = 0; i < 4; ++i) {
        const int kk = kr + i*16;
        float4 wv = *(const float4*)(W + (size_t)(k0 + kk)*D_ + n0 + nc);
        Ts[nc+0][kk] = f2b(wv.x); Ts[nc+1][kk] = f2b(wv.y);
        Ts[nc+2][kk] = f2b(wv.z); Ts[nc+3][kk] = f2b(wv.w);
    }
    __syncthreads();
    const int nr = t >> 2, kc = (t & 3)*16;
    u16* dst = Wt + (size_t)(n0 + nr)*D_ + k0 + kc;
    *(uint4*)(dst)     = *(const uint4*)(&Ts[nr][kc]);
    *(uint4*)(dst + 8) = *(const uint4*)(&Ts[nr][kc + 8]);
}

// ---------------- QKV projection GEMM, one launch (z selects) ----------------
__global__ __launch_bounds__(256)
void proj_qkv(const u16* __restrict__ qb, const u16* __restrict__ kb,
              const u16* __restrict__ vb,
              const u16* __restrict__ Wqt, const u16* __restrict__ Wkt,
              const u16* __restrict__ Wvt,
              const float* __restrict__ bq, const float* __restrict__ bk,
              const float* __restrict__ bv,
              u16* __restrict__ Qhb, u16* __restrict__ Khb,
              u16* __restrict__ Vtb)
{
    const int z = blockIdx.z;
    const u16* Ab     = z==0 ? qb  : (z==1 ? kb  : vb);
    const u16* Wt     = z==0 ? Wqt : (z==1 ? Wkt : Wvt);
    const float* bias = z==0 ? bq  : (z==1 ? bk  : bv);

    const int lin = blockIdx.y*64 + blockIdx.x;      // 0..511
    const int cx = lin & 7, idx = lin >> 3;
    const int nx = cx*8 + (idx & 7), ny = idx >> 3;  // bijective
    const int m0 = nx*128, n0 = ny*128;

    __shared__ u16 AsU[128*64];
    __shared__ u16 BsU[128*64];
    const int t = threadIdx.x;
    const int w = t >> 6, lane = t & 63;
    const int lo = lane & 15, g4 = lane >> 4;
    const int wr = w >> 1, wc = w & 1;
    const int wbase = w*64;

    const f32x4 zero = {0.f, 0.f, 0.f, 0.f};
    f32x4 acc[4][4];
    #pragma unroll
    for (int mi = 0; mi < 4; ++mi)
        #pragma unroll
        for (int ni = 0; ni < 4; ++ni) acc[mi][ni] = zero;

    for (int k0 = 0; k0 < 1024; k0 += 64) {
        __syncthreads();
        #pragma unroll
        for (int c = 0; c < 4; ++c) {
            const int sidx = c*256 + wbase + lane;
            const int row = sidx >> 3;
            const int gblk = (sidx & 7) ^ (row & 7);
            gl_lds16(Ab + (size_t)(m0+row)*D_ + k0 + gblk*8, AsU + (size_t)(c*256 + wbase)*8);
            gl_lds16(Wt + (size_t)(n0+row)*D_ + k0 + gblk*8, BsU + (size_t)(c*256 + wbase)*8);
        }
        __syncthreads();
        #pragma unroll
        for (int ks = 0; ks < 2; ++ks) {
            bf16x8 af[4], bfr[4];
            #pragma unroll
            for (int mi = 0; mi < 4; ++mi) {
                const int row = wr*64 + mi*16 + lo;
                af[mi] = *(const bf16x8*)(AsU + row*64 + (((ks*4+g4) ^ (lo&7))*8));
            }
            #pragma unroll
            for (int ni = 0; ni < 4; ++ni) {
                const int row = wc*64 + ni*16 + lo;
                bfr[ni] = *(const bf16x8*)(BsU + row*64 + (((ks*4+g4) ^ (lo&7))*8));
            }
            #pragma unroll
            for (int mi = 0; mi < 4; ++mi)
                #pragma unroll
                for (int ni = 0; ni < 4; ++ni)
                    acc[mi][ni] = __builtin_amdgcn_mfma_f32_16x16x32_bf16(
                        af[mi], bfr[ni], acc[mi][ni], 0, 0, 0);
        }
    }

    if (z < 2) {
        u16* C = z==0 ? Qhb : Khb;
        #pragma unroll
        for (int ni = 0; ni < 4; ++ni) {
            const int n = n0 + wc*64 + ni*16 + lo;
            const float bb = bias[n];
            #pragma unroll
            for (int mi = 0; mi < 4; ++mi)
                #pragma unroll
                for (int j = 0; j < 4; ++j) {
                    const size_t m = (size_t)(m0 + wr*64 + mi*16 + g4*4 + j);
                    C[m*D_ + n] = f2b(acc[mi][ni][j] + bb);
                }
        }
    } else {
        // transposed: Vt[b*D_ + n][s], s = within-batch row
        const int bb_ = m0 >> 11;
        const int sbase = (m0 & 2047) + wr*64;
        #pragma unroll
        for (int ni = 0; ni < 4; ++ni) {
            const int n = n0 + wc*64 + ni*16 + lo;
            const float bv_ = bias[n];
            u16* vrow = Vtb + (size_t)(bb_*D_ + n)*S_ + sbase;
            #pragma unroll
            for (int mi = 0; mi < 4; ++mi) {
                union { u16 u[4]; uint2 v2; } pk;
                #pragma unroll
                for (int j = 0; j < 4; ++j) pk.u[j] = f2b(acc[mi][ni][j] + bv_);
                *(uint2*)(vrow + mi*16 + g4*4) = pk.v2;  // 8B, aligned
            }
        }
    }
}

// ---------------- fused attention: SINGLE-WAVE blocks (round 12) -------------
// 1 wave = 32 q-rows, 4096 blocks. Waves retire/replace independently -> each
// CU carries a mix of loop1-phase and loop2-phase waves, so the 1.07 GB nt
// store stream overlaps other waves' QK^T/exp compute (breaks phase lockstep).
// XCD swizzle: cx = lin&7 -> each XCD owns 8 (b,h) pairs = 4 MB K/V (L2-fit).
__global__ __launch_bounds__(64)
void attn_fused2(const u16* __restrict__ Qh, const u16* __restrict__ Kh,
                 const u16* __restrict__ Vt,
                 u16* __restrict__ ctxb, float* __restrict__ attn)
{
    __shared__ u16 Pw[2048];        // 32q x 64key, XOR-swizzled (per-wave)
    const int lane = threadIdx.x;
    const int lo = lane & 15, g4 = lane >> 4;

    const int lin = blockIdx.x;                   // 0..4095
    const int cx = lin & 7, idx = lin >> 3;
    const int nl = cx*512 + idx;                  // bijective chunked
    const int qt = nl & 63, bh = nl >> 6;
    const int h = bh & 15, b = bh >> 4;
    const int qbase = qt*32;

    bf16x8 qf[2][2];
    #pragma unroll
    for (int qs = 0; qs < 2; ++qs)
        #pragma unroll
        for (int ks = 0; ks < 2; ++ks)
            qf[qs][ks] = *(const bf16x8*)(Qh + (size_t)(b*S_ + qbase + qs*16 + lo)*D_ + h*DH_ + ks*32 + g4*8);

    const f32x4 zero = {0.f, 0.f, 0.f, 0.f};

    // ---------------- loop1: rowsums only ----------------
    float rs[2][4] = {};
    for (int kt = 0; kt < 32; ++kt) {
        const size_t kbase = (size_t)(b*S_ + kt*64)*D_ + h*DH_;
        f32x4 sacc[2][4];
        #pragma unroll
        for (int qs = 0; qs < 2; ++qs)
            #pragma unroll
            for (int ni = 0; ni < 4; ++ni) sacc[qs][ni] = zero;
        __builtin_amdgcn_s_setprio(1);
        #pragma unroll
        for (int ks = 0; ks < 2; ++ks)
            #pragma unroll
            for (int ni = 0; ni < 4; ++ni) {
                const bf16x8 kf = *(const bf16x8*)(Kh + kbase + (size_t)(ni*16 + lo)*D_ + ks*32 + g4*8);
                sacc[0][ni] = __builtin_amdgcn_mfma_f32_16x16x32_bf16(qf[0][ks], kf, sacc[0][ni], 0, 0, 0);
                sacc[1][ni] = __builtin_amdgcn_mfma_f32_16x16x32_bf16(qf[1][ks], kf, sacc[1][ni], 0, 0, 0);
            }
        __builtin_amdgcn_s_setprio(0);
        #pragma unroll
        for (int qs = 0; qs < 2; ++qs)
            #pragma unroll
            for (int ni = 0; ni < 4; ++ni)
                #pragma unroll
                for (int j = 0; j < 4; ++j)
                    rs[qs][j] += __expf(sacc[qs][ni][j] * 0.125f);
    }

    float invp[2][4];
    #pragma unroll
    for (int qs = 0; qs < 2; ++qs)
        #pragma unroll
        for (int j = 0; j < 4; ++j) {
            float r = rs[qs][j];
            r += __shfl_xor(r, 1); r += __shfl_xor(r, 2);
            r += __shfl_xor(r, 4); r += __shfl_xor(r, 8);
            invp[qs][j] = 1.0f / r;
        }

    // ---------------- loop2: recompute + store + PV ----------------
    size_t vtb[4];
    #pragma unroll
    for (int ni = 0; ni < 4; ++ni)
        vtb[ni] = (size_t)(b*D_ + h*DH_ + ni*16 + lo)*S_;

    // attn row base for this lane's rows: q = qbase + qs*16 + g4*4 + j
    float* abase = attn + ((size_t)(b*H_ + h)*S_ + qbase + g4*4)*S_;

    f32x4 cacc[2][4];
    #pragma unroll
    for (int qs = 0; qs < 2; ++qs)
        #pragma unroll
        for (int ni = 0; ni < 4; ++ni) cacc[qs][ni] = zero;

    for (int kt = 0; kt < 32; ++kt) {
        const size_t kbase = (size_t)(b*S_ + kt*64)*D_ + h*DH_;
        f32x4 sacc[2][4];
        #pragma unroll
        for (int qs = 0; qs < 2; ++qs)
            #pragma unroll
            for (int ni = 0; ni < 4; ++ni) sacc[qs][ni] = zero;
        __builtin_amdgcn_s_setprio(1);
        #pragma unroll
        for (int ks = 0; ks < 2; ++ks)
            #pragma unroll
            for (int ni = 0; ni < 4; ++ni) {
                const bf16x8 kf = *(const bf16x8*)(Kh + kbase + (size_t)(ni*16 + lo)*D_ + ks*32 + g4*8);
                sacc[0][ni] = __builtin_amdgcn_mfma_f32_16x16x32_bf16(qf[0][ks], kf, sacc[0][ni], 0, 0, 0);
                sacc[1][ni] = __builtin_amdgcn_mfma_f32_16x16x32_bf16(qf[1][ks], kf, sacc[1][ni], 0, 0, 0);
            }
        __builtin_amdgcn_s_setprio(0);
        // exp -> P LDS (unnormalized) + nt-store normalized attn
        #pragma unroll
        for (int qs = 0; qs < 2; ++qs)
            #pragma unroll
            for (int ni = 0; ni < 4; ++ni)
                #pragma unroll
                for (int j = 0; j < 4; ++j) {
                    const float p = __expf(sacc[qs][ni][j] * 0.125f);
                    const int row = qs*16 + g4*4 + j, key = ni*16 + lo;
                    Pw[row*64 + (((key >> 3) ^ (row & 7))*8) + (key & 7)] = f2b(p);
                    __builtin_nontemporal_store(p * invp[qs][j],
                        abase + ((size_t)(qs*16 + j))*S_ + kt*64 + key);
                }
        __builtin_amdgcn_s_setprio(1);
        #pragma unroll
        for (int ks = 0; ks < 2; ++ks) {
            bf16x8 vf[4];
            #pragma unroll
            for (int ni = 0; ni < 4; ++ni)
                vf[ni] = *(const bf16x8*)(Vt + vtb[ni] + kt*64 + ks*32 + g4*8);
            #pragma unroll
            for (int qs = 0; qs < 2; ++qs) {
                const int prow = qs*16 + lo;
                const bf16x8 pa = *(const bf16x8*)(Pw + prow*64 + (((ks*4 + g4) ^ (lo & 7))*8));
                #pragma unroll
                for (int ni = 0; ni < 4; ++ni)
                    cacc[qs][ni] = __builtin_amdgcn_mfma_f32_16x16x32_bf16(pa, vf[ni], cacc[qs][ni], 0, 0, 0);
            }
        }
        __builtin_amdgcn_s_setprio(0);
    }

    #pragma unroll
    for (int qs = 0; qs < 2; ++qs)
        #pragma unroll
        for (int j = 0; j < 4; ++j) {
            const float inv = invp[qs][j];
            #pragma unroll
            for (int ni = 0; ni < 4; ++ni)
                ctxb[(size_t)(b*S_ + qbase + qs*16 + g4*4 + j)*D_ + h*DH_ + ni*16 + lo] =
                    f2b(cacc[qs][ni][j] * inv);
        }
}

// ---------------- output GEMM: out[M][1024] = ctx@Wo + bo (fp32 out) ---------
__global__ __launch_bounds__(256)
void gemm_out(const u16* __restrict__ Ab, const u16* __restrict__ Wt,
              const float* __restrict__ bias, float* __restrict__ Cf)
{
    const int lin = blockIdx.y*64 + blockIdx.x;
    const int cx = lin & 7, idx = lin >> 3;
    const int nx = cx*8 + (idx & 7), ny = idx >> 3;
    const int m0 = nx*128, n0 = ny*128;

    __shared__ u16 AsU[128*64];
    __shared__ u16 BsU[128*64];
    const int t = threadIdx.x;
    const int w = t >> 6, lane = t & 63;
    const int lo = lane & 15, g4 = lane >> 4;
    const int wr = w >> 1, wc = w & 1;
    const int wbase = w*64;

    const f32x4 zero = {0.f, 0.f, 0.f, 0.f};
    f32x4 acc[4][4];
    #pragma unroll
    for (int mi = 0; mi < 4; ++mi)
        #pragma unroll
        for (int ni = 0; ni < 4; ++ni) acc[mi][ni] = zero;

    for (int k0 = 0; k0 < 1024; k0 += 64) {
        __syncthreads();
        #pragma unroll
        for (int c = 0; c < 4; ++c) {
            const int sidx = c*256 + wbase + lane;
            const int row = sidx >> 3;
            const int gblk = (sidx & 7) ^ (row & 7);
            gl_lds16(Ab + (size_t)(m0+row)*D_ + k0 + gblk*8, AsU + (size_t)(c*256 + wbase)*8);
            gl_lds16(Wt + (size_t)(n0+row)*D_ + k0 + gblk*8, BsU + (size_t)(c*256 + wbase)*8);
        }
        __syncthreads();
        #pragma unroll
        for (int ks = 0; ks < 2; ++ks) {
            bf16x8 af[4], bfr[4];
            #pragma unroll
            for (int mi = 0; mi < 4; ++mi) {
                const int row = wr*64 + mi*16 + lo;
                af[mi] = *(const bf16x8*)(AsU + row*64 + (((ks*4+g4) ^ (lo&7))*8));
            }
            #pragma unroll
            for (int ni = 0; ni < 4; ++ni) {
                const int row = wc*64 + ni*16 + lo;
                bfr[ni] = *(const bf16x8*)(BsU + row*64 + (((ks*4+g4) ^ (lo&7))*8));
            }
            #pragma unroll
            for (int mi = 0; mi < 4; ++mi)
                #pragma unroll
                for (int ni = 0; ni < 4; ++ni)
                    acc[mi][ni] = __builtin_amdgcn_mfma_f32_16x16x32_bf16(
                        af[mi], bfr[ni], acc[mi][ni], 0, 0, 0);
        }
    }

    #pragma unroll
    for (int ni = 0; ni < 4; ++ni) {
        const int n = n0 + wc*64 + ni*16 + lo;
        const float bb = bias[n];
        #pragma unroll
        for (int mi = 0; mi < 4; ++mi)
            #pragma unroll
            for (int j = 0; j < 4; ++j) {
                const size_t m = (size_t)(m0 + wr*64 + mi*16 + g4*4 + j);
                Cf[m*D_ + n] = acc[mi][ni][j] + bb;
            }
    }
}

// ----------------------------------------------------------------------------
extern "C" void kernel_launch(void* const* d_in, const int* in_sizes, int n_in,
                              void* d_out, int out_size, void* d_ws, size_t ws_size,
                              hipStream_t stream)
{
    (void)in_sizes; (void)n_in; (void)out_size; (void)ws_size;
    const float* v  = (const float*)d_in[0];
    const float* k  = (const float*)d_in[1];
    const float* q  = (const float*)d_in[2];
    const float* Wq = (const float*)d_in[3];
    const float* bq = (const float*)d_in[4];
    const float* Wk = (const float*)d_in[5];
    const float* bk = (const float*)d_in[6];
    const float* Wv = (const float*)d_in[7];
    const float* bv = (const float*)d_in[8];
    const float* Wo = (const float*)d_in[9];
    const float* bo = (const float*)d_in[10];

    float* out  = (float*)d_out;                  // (B,S,D) fp32
    float* attn = out + (size_t)M_*D_;            // (B,H,S,S) fp32

    u16* qb  = (u16*)d_ws;
    u16* kb  = qb  + (size_t)M_*D_;
    u16* vb  = kb  + (size_t)M_*D_;
    u16* Wqt = vb  + (size_t)M_*D_;
    u16* Wkt = Wqt + (size_t)D_*D_;
    u16* Wvt = Wkt + (size_t)D_*D_;
    u16* Wot = Wvt + (size_t)D_*D_;
    u16* Qhb = Wot + (size_t)D_*D_;
    u16* Khb = Qhb + (size_t)M_*D_;
    u16* Vtb = Khb + (size_t)M_*D_;
    u16* ctxb = qb;                               // reuse (dead after q-proj)

    dim3 b256(256);

    cvt3       <<<dim3(4096, 3),   b256, 0, stream>>>(q, k, v, qb, kb, vb);
    wtrans4    <<<dim3(16, 16, 4), b256, 0, stream>>>(Wq, Wk, Wv, Wo, Wqt, Wkt, Wvt, Wot);
    proj_qkv   <<<dim3(64, 8, 3),  b256, 0, stream>>>(qb, kb, vb, Wqt, Wkt, Wvt,
                                                      bq, bk, bv, Qhb, Khb, Vtb);
    attn_fused2<<<dim3(4096), dim3(64), 0, stream>>>(Qhb, Khb, Vtb, ctxb, attn);
    gemm_out   <<<dim3(64, 8),     b256, 0, stream>>>(ctxb, Wot, bo, out);
}

// Round 13
// 468.699 us; speedup vs baseline: 1.4447x; 1.0881x over previous
//
#include <hip/hip_runtime.h>
#include <hip/hip_bf16.h>

#define B_  4
#define S_  2048
#define D_  1024
#define H_  16
#define DH_ 64
#define M_  (B_*S_)   // 8192

typedef short bf16x8 __attribute__((ext_vector_type(8)));   // 8 bf16 = 4 VGPR
typedef float f32x4  __attribute__((ext_vector_type(4)));
typedef unsigned short u16;

__device__ __forceinline__ u16 f2b(float x) {
    union { __hip_bfloat16 h; u16 u; } c; c.h = __float2bfloat16(x); return c.u;
}

// global -> LDS direct (16B per lane). LDS dst is wave-uniform base + lane*16;
// global src is per-lane (pre-swizzle applied there, rule #21/m173).
__device__ __forceinline__ void gl_lds16(const u16* g, u16* l) {
    __builtin_amdgcn_global_load_lds(
        (const __attribute__((address_space(1))) unsigned int*)g,
        (__attribute__((address_space(3))) unsigned int*)l,
        16, 0, 0);
}

// ---------------- fp32 -> bf16 bulk convert, q/k/v in one launch -------------
__global__ __launch_bounds__(256)
void cvt3(const float* __restrict__ q, const float* __restrict__ k,
          const float* __restrict__ v,
          u16* __restrict__ qb, u16* __restrict__ kb, u16* __restrict__ vb)
{
    const float* src = blockIdx.y == 0 ? q : (blockIdx.y == 1 ? k : v);
    u16*         dst = blockIdx.y == 0 ? qb : (blockIdx.y == 1 ? kb : vb);
    const int i = blockIdx.x*256 + threadIdx.x;      // 0..2^20-1 exact
    float4 a = ((const float4*)src)[2*i];
    float4 b = ((const float4*)src)[2*i+1];
    union { u16 u[8]; uint4 v4; } r;
    r.u[0]=f2b(a.x); r.u[1]=f2b(a.y); r.u[2]=f2b(a.z); r.u[3]=f2b(a.w);
    r.u[4]=f2b(b.x); r.u[5]=f2b(b.y); r.u[6]=f2b(b.z); r.u[7]=f2b(b.w);
    ((uint4*)dst)[i] = r.v4;
}

// ---------------- W[k][n] fp32 -> Wt[n][k] bf16, all four in one launch ------
__global__ __launch_bounds__(256)
void wtrans4(const float* __restrict__ Wq, const float* __restrict__ Wk,
             const float* __restrict__ Wv, const float* __restrict__ Wo,
             u16* __restrict__ Wqt, u16* __restrict__ Wkt,
             u16* __restrict__ Wvt, u16* __restrict__ Wot)
{
    const int z = blockIdx.z;
    const float* W  = z==0 ? Wq  : (z==1 ? Wk  : (z==2 ? Wv  : Wo));
    u16*         Wt = z==0 ? Wqt : (z==1 ? Wkt : (z==2 ? Wvt : Wot));
    __shared__ u16 Ts[64][80];
    const int t = threadIdx.x;
    const int k0 = blockIdx.x*64, n0 = blockIdx.y*64;
    const int kr = t >> 4, nc = (t & 15)*4;
    #pragma unroll
    for (int i = 0; i < 4; ++i) {
        const int kk = kr + i*16;
        float4 wv = *(const float4*)(W + (size_t)(k0 + kk)*D_ + n0 + nc);
        Ts[nc+0][kk] = f2b(wv.x); Ts[nc+1][kk] = f2b(wv.y);
        Ts[nc+2][kk] = f2b(wv.z); Ts[nc+3][kk] = f2b(wv.w);
    }
    __syncthreads();
    const int nr = t >> 2, kc = (t & 3)*16;
    u16* dst = Wt + (size_t)(n0 + nr)*D_ + k0 + kc;
    *(uint4*)(dst)     = *(const uint4*)(&Ts[nr][kc]);
    *(uint4*)(dst + 8) = *(const uint4*)(&Ts[nr][kc + 8]);
}

// ---------------- QKV projection GEMM, one launch (z selects) ----------------
__global__ __launch_bounds__(256)
void proj_qkv(const u16* __restrict__ qb, const u16* __restrict__ kb,
              const u16* __restrict__ vb,
              const u16* __restrict__ Wqt, const u16* __restrict__ Wkt,
              const u16* __restrict__ Wvt,
              const float* __restrict__ bq, const float* __restrict__ bk,
              const float* __restrict__ bv,
              u16* __restrict__ Qhb, u16* __restrict__ Khb,
              u16* __restrict__ Vtb)
{
    const int z = blockIdx.z;
    const u16* Ab     = z==0 ? qb  : (z==1 ? kb  : vb);
    const u16* Wt     = z==0 ? Wqt : (z==1 ? Wkt : Wvt);
    const float* bias = z==0 ? bq  : (z==1 ? bk  : bv);

    const int lin = blockIdx.y*64 + blockIdx.x;      // 0..511
    const int cx = lin & 7, idx = lin >> 3;
    const int nx = cx*8 + (idx & 7), ny = idx >> 3;  // bijective
    const int m0 = nx*128, n0 = ny*128;

    __shared__ u16 AsU[128*64];
    __shared__ u16 BsU[128*64];
    const int t = threadIdx.x;
    const int w = t >> 6, lane = t & 63;
    const int lo = lane & 15, g4 = lane >> 4;
    const int wr = w >> 1, wc = w & 1;
    const int wbase = w*64;

    const f32x4 zero = {0.f, 0.f, 0.f, 0.f};
    f32x4 acc[4][4];
    #pragma unroll
    for (int mi = 0; mi < 4; ++mi)
        #pragma unroll
        for (int ni = 0; ni < 4; ++ni) acc[mi][ni] = zero;

    for (int k0 = 0; k0 < 1024; k0 += 64) {
        __syncthreads();
        #pragma unroll
        for (int c = 0; c < 4; ++c) {
            const int sidx = c*256 + wbase + lane;
            const int row = sidx >> 3;
            const int gblk = (sidx & 7) ^ (row & 7);
            gl_lds16(Ab + (size_t)(m0+row)*D_ + k0 + gblk*8, AsU + (size_t)(c*256 + wbase)*8);
            gl_lds16(Wt + (size_t)(n0+row)*D_ + k0 + gblk*8, BsU + (size_t)(c*256 + wbase)*8);
        }
        __syncthreads();
        #pragma unroll
        for (int ks = 0; ks < 2; ++ks) {
            bf16x8 af[4], bfr[4];
            #pragma unroll
            for (int mi = 0; mi < 4; ++mi) {
                const int row = wr*64 + mi*16 + lo;
                af[mi] = *(const bf16x8*)(AsU + row*64 + (((ks*4+g4) ^ (lo&7))*8));
            }
            #pragma unroll
            for (int ni = 0; ni < 4; ++ni) {
                const int row = wc*64 + ni*16 + lo;
                bfr[ni] = *(const bf16x8*)(BsU + row*64 + (((ks*4+g4) ^ (lo&7))*8));
            }
            #pragma unroll
            for (int mi = 0; mi < 4; ++mi)
                #pragma unroll
                for (int ni = 0; ni < 4; ++ni)
                    acc[mi][ni] = __builtin_amdgcn_mfma_f32_16x16x32_bf16(
                        af[mi], bfr[ni], acc[mi][ni], 0, 0, 0);
        }
    }

    if (z < 2) {
        u16* C = z==0 ? Qhb : Khb;
        #pragma unroll
        for (int ni = 0; ni < 4; ++ni) {
            const int n = n0 + wc*64 + ni*16 + lo;
            const float bb = bias[n];
            #pragma unroll
            for (int mi = 0; mi < 4; ++mi)
                #pragma unroll
                for (int j = 0; j < 4; ++j) {
                    const size_t m = (size_t)(m0 + wr*64 + mi*16 + g4*4 + j);
                    C[m*D_ + n] = f2b(acc[mi][ni][j] + bb);
                }
        }
    } else {
        // transposed: Vt[b*D_ + n][s], s = within-batch row
        const int bb_ = m0 >> 11;
        const int sbase = (m0 & 2047) + wr*64;
        #pragma unroll
        for (int ni = 0; ni < 4; ++ni) {
            const int n = n0 + wc*64 + ni*16 + lo;
            const float bv_ = bias[n];
            u16* vrow = Vtb + (size_t)(bb_*D_ + n)*S_ + sbase;
            #pragma unroll
            for (int mi = 0; mi < 4; ++mi) {
                union { u16 u[4]; uint2 v2; } pk;
                #pragma unroll
                for (int j = 0; j < 4; ++j) pk.u[j] = f2b(acc[mi][ni][j] + bv_);
                *(uint2*)(vrow + mi*16 + g4*4) = pk.v2;  // 8B, aligned
            }
        }
    }
}

// ---------------- fused attention v3: block-level LDS staging (round 13) -----
// 4 waves x 32q = 128 q rows per block, grid 1024. K-tile (and V-tile in
// loop2) staged ONCE per block per kt into LDS via global_load_lds -> L2 read
// traffic drops 4x (3.2GB -> 0.8GB), easing the 4MB-per-XCD K/V capacity
// thrash that the plain-vs-nt store A/B exposed. m97 2-barrier structure.
__global__ __launch_bounds__(256)
void attn_fused3(const u16* __restrict__ Qh, const u16* __restrict__ Kh,
                 const u16* __restrict__ Vt,
                 u16* __restrict__ ctxb, float* __restrict__ attn)
{
    __shared__ u16 Kbuf[64*64];     // 8KB, chunk-swizzled
    __shared__ u16 Vbuf[64*64];     // 8KB
    __shared__ u16 Plds[4*2048];    // per-wave 32q x 64key, XOR-swizzled
    const int t = threadIdx.x, w = t >> 6, lane = t & 63;
    const int lo = lane & 15, g4 = lane >> 4;
    const int wbase = w*64;

    const int lin = (blockIdx.z*16 + blockIdx.y)*16 + blockIdx.x;  // 0..1023
    const int cx = lin & 7, idx = lin >> 3;
    const int nl = cx*128 + idx;                  // bijective chunked
    const int qb_ = nl & 15, bh = nl >> 4;
    const int h = bh & 15, b = bh >> 4;
    const int qbase = qb_*128 + w*32;
    u16* Pw = Plds + w*2048;

    bf16x8 qf[2][2];
    #pragma unroll
    for (int qs = 0; qs < 2; ++qs)
        #pragma unroll
        for (int ks = 0; ks < 2; ++ks)
            qf[qs][ks] = *(const bf16x8*)(Qh + (size_t)(b*S_ + qbase + qs*16 + lo)*D_ + h*DH_ + ks*32 + g4*8);

    const f32x4 zero = {0.f, 0.f, 0.f, 0.f};

    // ---------------- loop1: rowsums only (K via LDS) ----------------
    float rs[2][4] = {};
    for (int kt = 0; kt < 32; ++kt) {
        __syncthreads();   // prev iter's Kbuf readers done
        #pragma unroll
        for (int c = 0; c < 2; ++c) {
            const int sidx = c*256 + wbase + lane;       // 0..511
            const int row = sidx >> 3;                   // 0..63
            const int gblk = (sidx & 7) ^ (row & 7);
            gl_lds16(Kh + (size_t)(b*S_ + kt*64 + row)*D_ + h*DH_ + gblk*8,
                     Kbuf + (size_t)(c*256 + wbase)*8);
        }
        __syncthreads();   // staging complete
        f32x4 sacc[2][4];
        #pragma unroll
        for (int qs = 0; qs < 2; ++qs)
            #pragma unroll
            for (int ni = 0; ni < 4; ++ni) sacc[qs][ni] = zero;
        __builtin_amdgcn_s_setprio(1);
        #pragma unroll
        for (int ks = 0; ks < 2; ++ks)
            #pragma unroll
            for (int ni = 0; ni < 4; ++ni) {
                const int row = ni*16 + lo;
                const bf16x8 kf = *(const bf16x8*)(Kbuf + row*64 + (((ks*4+g4) ^ (lo&7))*8));
                sacc[0][ni] = __builtin_amdgcn_mfma_f32_16x16x32_bf16(qf[0][ks], kf, sacc[0][ni], 0, 0, 0);
                sacc[1][ni] = __builtin_amdgcn_mfma_f32_16x16x32_bf16(qf[1][ks], kf, sacc[1][ni], 0, 0, 0);
            }
        __builtin_amdgcn_s_setprio(0);
        #pragma unroll
        for (int qs = 0; qs < 2; ++qs)
            #pragma unroll
            for (int ni = 0; ni < 4; ++ni)
                #pragma unroll
                for (int j = 0; j < 4; ++j)
                    rs[qs][j] += __expf(sacc[qs][ni][j] * 0.125f);
    }

    float invp[2][4];
    #pragma unroll
    for (int qs = 0; qs < 2; ++qs)
        #pragma unroll
        for (int j = 0; j < 4; ++j) {
            float r = rs[qs][j];
            r += __shfl_xor(r, 1); r += __shfl_xor(r, 2);
            r += __shfl_xor(r, 4); r += __shfl_xor(r, 8);
            invp[qs][j] = 1.0f / r;
        }

    // ---------------- loop2: recompute + store + PV (K,V via LDS) ------------
    // attn row base for this lane's rows: q = qbase + qs*16 + g4*4 + j
    float* abase = attn + ((size_t)(b*H_ + h)*S_ + qbase + g4*4)*S_;

    f32x4 cacc[2][4];
    #pragma unroll
    for (int qs = 0; qs < 2; ++qs)
        #pragma unroll
        for (int ni = 0; ni < 4; ++ni) cacc[qs][ni] = zero;

    for (int kt = 0; kt < 32; ++kt) {
        __syncthreads();   // prev readers done (drains outstanding nt stores)
        #pragma unroll
        for (int c = 0; c < 2; ++c) {
            const int sidx = c*256 + wbase + lane;
            const int row = sidx >> 3;
            const int gblk = (sidx & 7) ^ (row & 7);
            gl_lds16(Kh + (size_t)(b*S_ + kt*64 + row)*D_ + h*DH_ + gblk*8,
                     Kbuf + (size_t)(c*256 + wbase)*8);
            gl_lds16(Vt + (size_t)(b*D_ + h*DH_ + row)*S_ + kt*64 + gblk*8,
                     Vbuf + (size_t)(c*256 + wbase)*8);
        }
        __syncthreads();   // staging complete
        f32x4 sacc[2][4];
        #pragma unroll
        for (int qs = 0; qs < 2; ++qs)
            #pragma unroll
            for (int ni = 0; ni < 4; ++ni) sacc[qs][ni] = zero;
        __builtin_amdgcn_s_setprio(1);
        #pragma unroll
        for (int ks = 0; ks < 2; ++ks)
            #pragma unroll
            for (int ni = 0; ni < 4; ++ni) {
                const int row = ni*16 + lo;
                const bf16x8 kf = *(const bf16x8*)(Kbuf + row*64 + (((ks*4+g4) ^ (lo&7))*8));
                sacc[0][ni] = __builtin_amdgcn_mfma_f32_16x16x32_bf16(qf[0][ks], kf, sacc[0][ni], 0, 0, 0);
                sacc[1][ni] = __builtin_amdgcn_mfma_f32_16x16x32_bf16(qf[1][ks], kf, sacc[1][ni], 0, 0, 0);
            }
        __builtin_amdgcn_s_setprio(0);
        // exp -> P LDS (unnormalized) + nt-store normalized attn
        #pragma unroll
        for (int qs = 0; qs < 2; ++qs)
            #pragma unroll
            for (int ni = 0; ni < 4; ++ni)
                #pragma unroll
                for (int j = 0; j < 4; ++j) {
                    const float p = __expf(sacc[qs][ni][j] * 0.125f);
                    const int row = qs*16 + g4*4 + j, key = ni*16 + lo;
                    Pw[row*64 + (((key >> 3) ^ (row & 7))*8) + (key & 7)] = f2b(p);
                    __builtin_nontemporal_store(p * invp[qs][j],
                        abase + ((size_t)(qs*16 + j))*S_ + kt*64 + key);
                }
        __builtin_amdgcn_s_setprio(1);
        #pragma unroll
        for (int ks = 0; ks < 2; ++ks) {
            bf16x8 vf[4];
            #pragma unroll
            for (int ni = 0; ni < 4; ++ni) {
                const int row = ni*16 + lo;
                vf[ni] = *(const bf16x8*)(Vbuf + row*64 + (((ks*4+g4) ^ (lo&7))*8));
            }
            #pragma unroll
            for (int qs = 0; qs < 2; ++qs) {
                const int prow = qs*16 + lo;
                const bf16x8 pa = *(const bf16x8*)(Pw + prow*64 + (((ks*4 + g4) ^ (lo & 7))*8));
                #pragma unroll
                for (int ni = 0; ni < 4; ++ni)
                    cacc[qs][ni] = __builtin_amdgcn_mfma_f32_16x16x32_bf16(pa, vf[ni], cacc[qs][ni], 0, 0, 0);
            }
        }
        __builtin_amdgcn_s_setprio(0);
    }

    #pragma unroll
    for (int qs = 0; qs < 2; ++qs)
        #pragma unroll
        for (int j = 0; j < 4; ++j) {
            const float inv = invp[qs][j];
            #pragma unroll
            for (int ni = 0; ni < 4; ++ni)
                ctxb[(size_t)(b*S_ + qbase + qs*16 + g4*4 + j)*D_ + h*DH_ + ni*16 + lo] =
                    f2b(cacc[qs][ni][j] * inv);
        }
}

// ---------------- output GEMM: out[M][1024] = ctx@Wo + bo (fp32 out) ---------
__global__ __launch_bounds__(256)
void gemm_out(const u16* __restrict__ Ab, const u16* __restrict__ Wt,
              const float* __restrict__ bias, float* __restrict__ Cf)
{
    const int lin = blockIdx.y*64 + blockIdx.x;
    const int cx = lin & 7, idx = lin >> 3;
    const int nx = cx*8 + (idx & 7), ny = idx >> 3;
    const int m0 = nx*128, n0 = ny*128;

    __shared__ u16 AsU[128*64];
    __shared__ u16 BsU[128*64];
    const int t = threadIdx.x;
    const int w = t >> 6, lane = t & 63;
    const int lo = lane & 15, g4 = lane >> 4;
    const int wr = w >> 1, wc = w & 1;
    const int wbase = w*64;

    const f32x4 zero = {0.f, 0.f, 0.f, 0.f};
    f32x4 acc[4][4];
    #pragma unroll
    for (int mi = 0; mi < 4; ++mi)
        #pragma unroll
        for (int ni = 0; ni < 4; ++ni) acc[mi][ni] = zero;

    for (int k0 = 0; k0 < 1024; k0 += 64) {
        __syncthreads();
        #pragma unroll
        for (int c = 0; c < 4; ++c) {
            const int sidx = c*256 + wbase + lane;
            const int row = sidx >> 3;
            const int gblk = (sidx & 7) ^ (row & 7);
            gl_lds16(Ab + (size_t)(m0+row)*D_ + k0 + gblk*8, AsU + (size_t)(c*256 + wbase)*8);
            gl_lds16(Wt + (size_t)(n0+row)*D_ + k0 + gblk*8, BsU + (size_t)(c*256 + wbase)*8);
        }
        __syncthreads();
        #pragma unroll
        for (int ks = 0; ks < 2; ++ks) {
            bf16x8 af[4], bfr[4];
            #pragma unroll
            for (int mi = 0; mi < 4; ++mi) {
                const int row = wr*64 + mi*16 + lo;
                af[mi] = *(const bf16x8*)(AsU + row*64 + (((ks*4+g4) ^ (lo&7))*8));
            }
            #pragma unroll
            for (int ni = 0; ni < 4; ++ni) {
                const int row = wc*64 + ni*16 + lo;
                bfr[ni] = *(const bf16x8*)(BsU + row*64 + (((ks*4+g4) ^ (lo&7))*8));
            }
            #pragma unroll
            for (int mi = 0; mi < 4; ++mi)
                #pragma unroll
                for (int ni = 0; ni < 4; ++ni)
                    acc[mi][ni] = __builtin_amdgcn_mfma_f32_16x16x32_bf16(
                        af[mi], bfr[ni], acc[mi][ni], 0, 0, 0);
        }
    }

    #pragma unroll
    for (int ni = 0; ni < 4; ++ni) {
        const int n = n0 + wc*64 + ni*16 + lo;
        const float bb = bias[n];
        #pragma unroll
        for (int mi = 0; mi < 4; ++mi)
            #pragma unroll
            for (int j = 0; j < 4; ++j) {
                const size_t m = (size_t)(m0 + wr*64 + mi*16 + g4*4 + j);
                Cf[m*D_ + n] = acc[mi][ni][j] + bb;
            }
    }
}

// ----------------------------------------------------------------------------
extern "C" void kernel_launch(void* const* d_in, const int* in_sizes, int n_in,
                              void* d_out, int out_size, void* d_ws, size_t ws_size,
                              hipStream_t stream)
{
    (void)in_sizes; (void)n_in; (void)out_size; (void)ws_size;
    const float* v  = (const float*)d_in[0];
    const float* k  = (const float*)d_in[1];
    const float* q  = (const float*)d_in[2];
    const float* Wq = (const float*)d_in[3];
    const float* bq = (const float*)d_in[4];
    const float* Wk = (const float*)d_in[5];
    const float* bk = (const float*)d_in[6];
    const float* Wv = (const float*)d_in[7];
    const float* bv = (const float*)d_in[8];
    const float* Wo = (const float*)d_in[9];
    const float* bo = (const float*)d_in[10];

    float* out  = (float*)d_out;                  // (B,S,D) fp32
    float* attn = out + (size_t)M_*D_;            // (B,H,S,S) fp32

    u16* qb  = (u16*)d_ws;
    u16* kb  = qb  + (size_t)M_*D_;
    u16* vb  = kb  + (size_t)M_*D_;
    u16* Wqt = vb  + (size_t)M_*D_;
    u16* Wkt = Wqt + (size_t)D_*D_;
    u16* Wvt = Wkt + (size_t)D_*D_;
    u16* Wot = Wvt + (size_t)D_*D_;
    u16* Qhb = Wot + (size_t)D_*D_;
    u16* Khb = Qhb + (size_t)M_*D_;
    u16* Vtb = Khb + (size_t)M_*D_;
    u16* ctxb = qb;                               // reuse (dead after q-proj)

    dim3 b256(256);

    cvt3       <<<dim3(4096, 3),   b256, 0, stream>>>(q, k, v, qb, kb, vb);
    wtrans4    <<<dim3(16, 16, 4), b256, 0, stream>>>(Wq, Wk, Wv, Wo, Wqt, Wkt, Wvt, Wot);
    proj_qkv   <<<dim3(64, 8, 3),  b256, 0, stream>>>(qb, kb, vb, Wqt, Wkt, Wvt,
                                                      bq, bk, bv, Qhb, Khb, Vtb);
    attn_fused3<<<dim3(16, 16, 4), b256, 0, stream>>>(Qhb, Khb, Vtb, ctxb, attn);
    gemm_out   <<<dim3(64, 8),     b256, 0, stream>>>(ctxb, Wot, bo, out);
}